// Round 5
// baseline (10012.052 us; speedup 1.0000x reference)
//
#include <hip/hip_runtime.h>

// Problem constants
#define BB   32      // batch
#define TT_  512     // sequence length
#define DD   1024    // input dim
#define HH   1024    // hidden
#define RR_  64      // low-rank
#define FH   4096    // 4*H
#define TC   32      // timestep chunk
#define NCMB 4224    // combined Wm(4096) + A(64) + pad(64) rows

typedef __attribute__((ext_vector_type(8))) short          bf16x8;   // MFMA A/B frag
typedef __attribute__((ext_vector_type(4))) float          f32x4;    // MFMA C/D frag
typedef __attribute__((ext_vector_type(4))) unsigned short us4;

// fp32 -> bf16 bits, round-to-nearest-even
__device__ __forceinline__ unsigned short f2bf(float x) {
    union { float f; unsigned u; } v; v.f = x;
    return (unsigned short)((v.u + 0x7FFFu + ((v.u >> 16) & 1u)) >> 16);
}

// ---------------------------------------------------------------------------
// Zero-init (ws poisoned 0xAA before every call)
// ---------------------------------------------------------------------------
__global__ void init_zero(float4* p, int n4) {
    int i = blockIdx.x * blockDim.x + threadIdx.x;
    if (i < n4) p[i] = make_float4(0.f, 0.f, 0.f, 0.f);
}

// fp32 -> bf16 bulk convert (weights, once per call)
__global__ void cvt_bf16(const float* __restrict__ src,
                         unsigned short* __restrict__ dst, int n4) {
    int i = blockIdx.x * blockDim.x + threadIdx.x;
    int stride = gridDim.x * blockDim.x;
    for (; i < n4; i += stride) {
        float4 v = ((const float4*)src)[i];
        us4 t; t.x = f2bf(v.x); t.y = f2bf(v.y); t.z = f2bf(v.z); t.w = f2bf(v.w);
        ((us4*)dst)[i] = t;
    }
}

// combined bias: bWm (4096) ++ zeros (128)
__global__ void fill_bcomb(const float* __restrict__ bWm, float* __restrict__ bcomb) {
    int i = blockIdx.x * blockDim.x + threadIdx.x;
    if (i < NCMB) bcomb[i] = (i < FH) ? bWm[i] : 0.f;
}

// x chunk -> bf16, layout [tt][b][1024]
__global__ void cvt_x_chunk(const float* __restrict__ x,
                            unsigned short* __restrict__ xbfc, int t0) {
    int id = blockIdx.x * blockDim.x + threadIdx.x;   // 65536 threads
    for (int u = id; u < 32 * 32 * 256; u += 65536) { // float4 units
        int d4 = u & 255, b = (u >> 8) & 31, tt = u >> 13;
        float4 v = *(const float4*)&x[(((long)b * TT_) + t0 + tt) * DD + (d4 << 2)];
        us4 o; o.x = f2bf(v.x); o.y = f2bf(v.y); o.z = f2bf(v.z); o.w = f2bf(v.w);
        *(us4*)&xbfc[(((long)tt * 32 + b) << 10) + (d4 << 2)] = o;
    }
}

// ---------------------------------------------------------------------------
// bf16-in bf16-MFMA GEMM, fp32 transposed output: C[((m>>5)*N + n)*32 + (m&31)]
// A row m = tt*32 + b at Abase + (m>>5)*strideT + (m&31)*strideB (bf16 elems).
// BK=64, XOR-swizzled LDS (byte ^= (row&7)<<4) — conflict-free ds_read_b128.
// 4 waves 2x2, per-wave 32x64 output (MI=2, NI=4), fp32 accumulate.
// ---------------------------------------------------------------------------
template<int BM, int BN>
__global__ __launch_bounds__(256) void gemm_bf(
    const unsigned short* __restrict__ Abase, long strideT, long strideB,
    const unsigned short* __restrict__ W, const float* __restrict__ bias,
    float* __restrict__ C, int N, int K)
{
    constexpr int BK  = 64;
    constexpr int WTM = BM / 2, WTN = BN / 2;      // 32, 64
    constexpr int MI  = WTM / 16, NI = WTN / 16;   // 2, 4
    constexpr int AU  = BM * 8 / 256;              // 16B units per thread (A)
    constexpr int BU  = BN * 8 / 256;              // (B)

    __shared__ __align__(16) unsigned short As[BM * BK];  // 8 KB
    __shared__ __align__(16) unsigned short Bs[BN * BK];  // 16 KB

    const int tid  = threadIdx.x;
    const int lane = tid & 63, wave = tid >> 6;
    const int wm   = wave >> 1, wn = wave & 1;
    const int kg   = lane >> 4;
    const int lr   = lane & 15;
    const long bm  = (long)blockIdx.y * BM;
    const long bn  = (long)blockIdx.x * BN;

    const unsigned short* ag[AU]; int ast[AU];
    const unsigned short* bg[BU]; int bst[BU];
#pragma unroll
    for (int i = 0; i < AU; ++i) {
        int u = i * 256 + tid, row = u >> 3, uc = u & 7;
        long m = bm + row;
        ag[i]  = Abase + (m >> 5) * strideT + (m & 31) * strideB + uc * 8;
        ast[i] = (row * 128 + uc * 16) ^ ((row & 7) << 4);
    }
#pragma unroll
    for (int i = 0; i < BU; ++i) {
        int u = i * 256 + tid, row = u >> 3, uc = u & 7;
        bg[i]  = W + (long)(bn + row) * K + uc * 8;
        bst[i] = (row * 128 + uc * 16) ^ ((row & 7) << 4);
    }

    f32x4 acc[MI][NI] = {};

    uint4 av[AU], bv[BU];
#pragma unroll
    for (int i = 0; i < AU; ++i) av[i] = *(const uint4*)(ag[i]);
#pragma unroll
    for (int i = 0; i < BU; ++i) bv[i] = *(const uint4*)(bg[i]);

    for (int k0 = 0; k0 < K; k0 += BK) {
        __syncthreads();
#pragma unroll
        for (int i = 0; i < AU; ++i) *(uint4*)((char*)As + ast[i]) = av[i];
#pragma unroll
        for (int i = 0; i < BU; ++i) *(uint4*)((char*)Bs + bst[i]) = bv[i];
        __syncthreads();

        if (k0 + BK < K) {
#pragma unroll
            for (int i = 0; i < AU; ++i) av[i] = *(const uint4*)(ag[i] + k0 + BK);
#pragma unroll
            for (int i = 0; i < BU; ++i) bv[i] = *(const uint4*)(bg[i] + k0 + BK);
        }

        bf16x8 af[MI][2], bfr[NI][2];
#pragma unroll
        for (int mi = 0; mi < MI; ++mi) {
            int row = wm * WTM + mi * 16 + lr;
            int rb = row * 128, sw = (row & 7) << 4;
#pragma unroll
            for (int kk = 0; kk < 2; ++kk)
                af[mi][kk] = *(const bf16x8*)((const char*)As +
                              (rb + ((kk * 64 + kg * 16) ^ sw)));
        }
#pragma unroll
        for (int ni = 0; ni < NI; ++ni) {
            int row = wn * WTN + ni * 16 + lr;
            int rb = row * 128, sw = (row & 7) << 4;
#pragma unroll
            for (int kk = 0; kk < 2; ++kk)
                bfr[ni][kk] = *(const bf16x8*)((const char*)Bs +
                              (rb + ((kk * 64 + kg * 16) ^ sw)));
        }
#pragma unroll
        for (int kk = 0; kk < 2; ++kk)
#pragma unroll
            for (int mi = 0; mi < MI; ++mi)
#pragma unroll
                for (int ni = 0; ni < NI; ++ni)
                    acc[mi][ni] = __builtin_amdgcn_mfma_f32_16x16x32_bf16(
                        af[mi][kk], bfr[ni][kk], acc[mi][ni], 0, 0, 0);
    }

    const int rbase = (lane >> 4) * 4;
#pragma unroll
    for (int mi = 0; mi < MI; ++mi) {
        long m0 = bm + wm * WTM + mi * 16 + rbase;
        long tt = m0 >> 5; int bq = (int)(m0 & 31);
#pragma unroll
        for (int ni = 0; ni < NI; ++ni) {
            long n = bn + wn * WTN + ni * 16 + lr;
            float bia = bias ? bias[n] : 0.f;
            float4 v = make_float4(acc[mi][ni][0] + bia, acc[mi][ni][1] + bia,
                                   acc[mi][ni][2] + bia, acc[mi][ni][3] + bia);
            *(float4*)&C[(tt * N + n) * 32 + bq] = v;
        }
    }
}

// ---------------------------------------------------------------------------
// Scan-step bodies (math identical to round-3/4). smem: [0,64K) h swizzled;
// [64K,72K) zsl[4][16][32]; [72K,80K) ssl[64][32] (mLSTM only).
// ---------------------------------------------------------------------------
__device__ __forceinline__ void slstm_body(
    int bx, const float* __restrict__ xwT,
    const unsigned short* __restrict__ Ubf, const float* __restrict__ bU,
    const float* __restrict__ alpha, const unsigned short* __restrict__ hin,
    unsigned short* __restrict__ hout, float* __restrict__ cst,
    unsigned short* __restrict__ out1t, char* smem)
{
    float* zsl = (float*)(smem + 65536);
    const int tid  = threadIdx.x;
    const int lane = tid & 63, wv = tid >> 6;
    const int j0   = bx * 16;
    const int lr   = lane & 15;
    const int koff = (lane >> 4) << 3;

    const uint4* hg = (const uint4*)hin;
#pragma unroll
    for (int i = 0; i < 16; ++i) {
        int u = tid + (i << 8);
        int o = u << 4;
        int sw = o ^ (((o >> 11) & 7) << 4);
        *(uint4*)(smem + sw) = hg[u];
    }
    __syncthreads();

    const unsigned short* Arow = Ubf + (((long)(wv * HH + j0 + lr)) << 10) + koff;
    const int base0 = lr * 2048 + koff * 2;
    const int base1 = (lr + 16) * 2048 + koff * 2;
    const int swz   = (lr & 7) << 4;

    f32x4 accZ0 = {0.f, 0.f, 0.f, 0.f}, accZ1 = {0.f, 0.f, 0.f, 0.f};
#pragma unroll 4
    for (int k0 = 0; k0 < 1024; k0 += 32) {
        bf16x8 a  = *(const bf16x8*)(Arow + k0);
        bf16x8 b0 = *(const bf16x8*)(smem + ((base0 + k0 * 2) ^ swz));
        bf16x8 b1 = *(const bf16x8*)(smem + ((base1 + k0 * 2) ^ swz));
        accZ0 = __builtin_amdgcn_mfma_f32_16x16x32_bf16(a, b0, accZ0, 0, 0, 0);
        accZ1 = __builtin_amdgcn_mfma_f32_16x16x32_bf16(a, b1, accZ1, 0, 0, 0);
    }
#pragma unroll
    for (int r = 0; r < 4; ++r) {
        int jj = ((lane >> 4) << 2) + r;
        zsl[wv * 512 + jj * 32 + lr]      = accZ0[r];
        zsl[wv * 512 + jj * 32 + lr + 16] = accZ1[r];
    }
    __syncthreads();

#pragma unroll
    for (int rep = 0; rep < 2; ++rep) {
        int p = (rep << 8) + tid;
        int j = p >> 5, b = p & 31;
        int n0 = j0 + j;
        float zi = xwT[(long)n0 * 32 + b]            + zsl[j * 32 + b]        + bU[n0];
        float zf = xwT[(long)(HH + n0) * 32 + b]     + zsl[512 + j * 32 + b]  + bU[HH + n0];
        float zo = xwT[(long)(2 * HH + n0) * 32 + b] + zsl[1024 + j * 32 + b] + bU[2 * HH + n0];
        float zg = xwT[(long)(3 * HH + n0) * 32 + b] + zsl[1536 + j * 32 + b] + bU[3 * HH + n0];
        float ig = 1.f / (1.f + expf(-zi));
        float fg = 1.f / (1.f + expf(-zf));
        float og = 1.f / (1.f + expf(-zo));
        float g  = tanhf(zg);
        float cold = cst[(long)b * HH + n0];
        float cn = alpha[n0] * (fg * cold + ig * g);
        float hn = og * tanhf(cn);
        unsigned short hb = f2bf(hn);
        cst[(long)b * HH + n0]  = cn;
        hout[(long)b * HH + n0] = hb;
        out1t[(long)b * HH + n0] = hb;    // bf16: same rounding GEMM applied before
    }
}

__device__ __forceinline__ void mlstm_body(
    int bx, const float* __restrict__ xwT,   // comb slice [4224][32]; xa at +4096*32
    const unsigned short* __restrict__ Ubf, const float* __restrict__ bU,
    const float* __restrict__ Pmat, const unsigned short* __restrict__ Bmbf,
    const unsigned short* __restrict__ hin,
    unsigned short* __restrict__ hout, float* __restrict__ cst,
    float* __restrict__ out, int t, char* smem)
{
    float* zsl = (float*)(smem + 65536);
    float* ssl = (float*)(smem + 65536 + 8192);
    const float* xaT = xwT + (long)FH * 32;
    const int tid  = threadIdx.x;
    const int lane = tid & 63, wv = tid >> 6;
    const int j0   = bx * 16;
    const int lr   = lane & 15;
    const int koff = (lane >> 4) << 3;

    const uint4* hg = (const uint4*)hin;
#pragma unroll
    for (int i = 0; i < 16; ++i) {
        int u = tid + (i << 8);
        int o = u << 4;
        int sw = o ^ (((o >> 11) & 7) << 4);
        *(uint4*)(smem + sw) = hg[u];
    }
    __syncthreads();

    const unsigned short* Arow = Ubf + (((long)(wv * HH + j0 + lr)) << 10) + koff;
    const unsigned short* Brow = Bmbf + (((long)(wv * 16 + lr)) << 10) + koff;
    const int base0 = lr * 2048 + koff * 2;
    const int base1 = (lr + 16) * 2048 + koff * 2;
    const int swz   = (lr & 7) << 4;

    f32x4 accZ0 = {0.f, 0.f, 0.f, 0.f}, accZ1 = {0.f, 0.f, 0.f, 0.f};
    f32x4 accS0 = {0.f, 0.f, 0.f, 0.f}, accS1 = {0.f, 0.f, 0.f, 0.f};
#pragma unroll 4
    for (int k0 = 0; k0 < 1024; k0 += 32) {
        bf16x8 a  = *(const bf16x8*)(Arow + k0);
        bf16x8 s  = *(const bf16x8*)(Brow + k0);
        bf16x8 b0 = *(const bf16x8*)(smem + ((base0 + k0 * 2) ^ swz));
        bf16x8 b1 = *(const bf16x8*)(smem + ((base1 + k0 * 2) ^ swz));
        accZ0 = __builtin_amdgcn_mfma_f32_16x16x32_bf16(a, b0, accZ0, 0, 0, 0);
        accZ1 = __builtin_amdgcn_mfma_f32_16x16x32_bf16(a, b1, accZ1, 0, 0, 0);
        accS0 = __builtin_amdgcn_mfma_f32_16x16x32_bf16(s, b0, accS0, 0, 0, 0);
        accS1 = __builtin_amdgcn_mfma_f32_16x16x32_bf16(s, b1, accS1, 0, 0, 0);
    }
#pragma unroll
    for (int r = 0; r < 4; ++r) {
        int jj = ((lane >> 4) << 2) + r;
        zsl[wv * 512 + jj * 32 + lr]      = accZ0[r];
        zsl[wv * 512 + jj * 32 + lr + 16] = accZ1[r];
        ssl[(wv * 16 + jj) * 32 + lr]      = accS0[r];
        ssl[(wv * 16 + jj) * 32 + lr + 16] = accS1[r];
    }
    __syncthreads();

#pragma unroll
    for (int i = 0; i < 8; ++i) {
        int idx = tid + (i << 8);
        ssl[idx] *= xaT[idx];
    }
    __syncthreads();

#pragma unroll
    for (int rep = 0; rep < 2; ++rep) {
        int p = (rep << 8) + tid;
        int j = p >> 5, b = p & 31;
        int n0 = j0 + j;
        float zi = xwT[(long)n0 * 32 + b]            + zsl[j * 32 + b]        + bU[n0];
        float zf = xwT[(long)(HH + n0) * 32 + b]     + zsl[512 + j * 32 + b]  + bU[HH + n0];
        float zo = xwT[(long)(2 * HH + n0) * 32 + b] + zsl[1024 + j * 32 + b] + bU[2 * HH + n0];
        float zg = xwT[(long)(3 * HH + n0) * 32 + b] + zsl[1536 + j * 32 + b] + bU[3 * HH + n0];
        float ig = 1.f / (1.f + expf(-zi));
        float fg = 1.f / (1.f + expf(-zf));
        float og = 1.f / (1.f + expf(-zo));
        float g  = tanhf(zg);
        const float* Pj = Pmat + (long)n0 * 64;
        float mx = 0.f;
#pragma unroll
        for (int r = 0; r < 64; ++r) mx += Pj[r] * ssl[r * 32 + b];
        float cold = cst[(long)b * HH + n0];
        float cn = fg * cold + ig * g + 0.1f * mx;
        float hn = og * tanhf(cn);
        cst[(long)b * HH + n0]  = cn;
        hout[(long)b * HH + n0] = f2bf(hn);
        out[(long)b * (TT_ * HH) + (long)t * HH + n0] = hn;
    }
}

// ---------------------------------------------------------------------------
// Fused pipelined step: blocks 0-63 sLSTM(ch); blocks 64-127 mLSTM(ch-1).
// ---------------------------------------------------------------------------
__global__ __launch_bounds__(256) void fused_step(
    const float* __restrict__ xwTs, const unsigned short* __restrict__ UbfS,
    const float* __restrict__ bUs, const float* __restrict__ alpha,
    const unsigned short* __restrict__ hsin, unsigned short* __restrict__ hsout,
    float* __restrict__ cS, unsigned short* __restrict__ out1t,
    const float* __restrict__ xwTm, const unsigned short* __restrict__ UbfM,
    const float* __restrict__ bUm, const float* __restrict__ Pmat,
    const unsigned short* __restrict__ Bmbf,
    const unsigned short* __restrict__ hmin, unsigned short* __restrict__ hmout,
    float* __restrict__ cM, float* __restrict__ out, int t,
    int do_s, int do_m)
{
    __shared__ __align__(16) char smem[81920];  // 80 KB
    const int bx = blockIdx.x;
    if (bx < 64) {
        if (do_s)
            slstm_body(bx, xwTs, UbfS, bUs, alpha, hsin, hsout, cS, out1t, smem);
    } else {
        if (do_m)
            mlstm_body(bx - 64, xwTm, UbfM, bUm, Pmat, Bmbf,
                       hmin, hmout, cM, out, t, smem);
    }
}

// ---------------------------------------------------------------------------
// Launch. ~71 MB workspace.
// ---------------------------------------------------------------------------
extern "C" void kernel_launch(void* const* d_in, const int* in_sizes, int n_in,
                              void* d_out, int out_size, void* d_ws, size_t ws_size,
                              hipStream_t stream) {
    const float* x     = (const float*)d_in[0];
    const float* Ws    = (const float*)d_in[1];
    const float* bWs   = (const float*)d_in[2];
    const float* Us    = (const float*)d_in[3];
    const float* bUs   = (const float*)d_in[4];
    const float* alpha = (const float*)d_in[5];
    const float* Wm    = (const float*)d_in[6];
    const float* bWm   = (const float*)d_in[7];
    const float* Um    = (const float*)d_in[8];
    const float* bUm   = (const float*)d_in[9];
    const float* A     = (const float*)d_in[10];
    const float* Bm    = (const float*)d_in[11];
    const float* P     = (const float*)d_in[12];
    float* out = (float*)d_out;

    // fp32 region
    float* xwTs  = (float*)d_ws;                      // TC*4096*32 = 4,194,304 f
    float* xwTm  = xwTs + (long)TC * FH * 32;         // TC*4224*32 = 4,325,376 f
    float* bcomb = xwTm + (long)TC * NCMB * 32;       // 4224 f
    // bf16 region
    unsigned short* out1c = (unsigned short*)(bcomb + NCMB);   // TC*B*H = 1,048,576 sh
    unsigned short* xbfc  = out1c + (long)TC * BB * HH;        // 1,048,576 sh
    unsigned short* Wsbf  = xbfc + (long)TC * BB * HH;         // 4,194,304 sh
    unsigned short* Wcomb = Wsbf + (long)FH * HH;              // 4,325,376 sh
    unsigned short* UbfS  = Wcomb + (long)NCMB * HH;           // 4,194,304 sh
    unsigned short* UbfM  = UbfS + (long)FH * HH;              // 4,194,304 sh
    unsigned short* Bmbf  = UbfM + (long)FH * HH;              // 65,536 sh
    // zeroed state region (contiguous): 4 h bufs bf16 + 2 c bufs fp32
    unsigned short* hbsA = Bmbf + (long)RR_ * HH;
    unsigned short* hbsB = hbsA + BB * HH;
    unsigned short* hbmA = hbsB + BB * HH;
    unsigned short* hbmB = hbmA + BB * HH;
    float* cS = (float*)(hbmB + BB * HH);
    float* cM = cS + BB * HH;
    // states: 4*64KB + 2*128KB = 512 KB = 32768 float4

    init_zero<<<128, 256, 0, stream>>>((float4*)hbsA, 32768);

    // one-time weight conversions
    cvt_bf16<<<2048, 256, 0, stream>>>(Us, UbfS, FH * HH / 4);
    cvt_bf16<<<2048, 256, 0, stream>>>(Um, UbfM, FH * HH / 4);
    cvt_bf16<<<64,   256, 0, stream>>>(Bm, Bmbf, RR_ * HH / 4);
    cvt_bf16<<<2048, 256, 0, stream>>>(Ws, Wsbf, FH * HH / 4);
    cvt_bf16<<<2048, 256, 0, stream>>>(Wm, Wcomb, FH * HH / 4);
    cvt_bf16<<<64,   256, 0, stream>>>(A, Wcomb + (long)FH * HH, RR_ * HH / 4);
    init_zero<<<32, 256, 0, stream>>>((float4*)(Wcomb + (long)(FH + RR_) * HH), 8192);
    fill_bcomb<<<17, 256, 0, stream>>>(bWm, bcomb);

    dim3 gxw(FH / 128, (TC * BB) / 64);    // (32, 16)
    dim3 gcm(NCMB / 128, (TC * BB) / 64);  // (33, 16)
    const int NC = TT_ / TC;               // 16

    for (int ch = 0; ch <= NC; ++ch) {
        const int do_s = (ch < NC), do_m = (ch > 0);

        if (do_s) {
            cvt_x_chunk<<<256, 256, 0, stream>>>(x, xbfc, ch * TC);
            gemm_bf<64, 128><<<gxw, 256, 0, stream>>>(
                xbfc, (long)BB * HH, (long)HH, Wsbf, bWs, xwTs, FH, HH);
        }

        for (int tt = 0; tt < TC; ++tt) {
            const unsigned short* hsin = (tt & 1) ? hbsB : hbsA;
            unsigned short* hsout      = (tt & 1) ? hbsA : hbsB;
            const unsigned short* hmin = (tt & 1) ? hbmB : hbmA;
            unsigned short* hmout      = (tt & 1) ? hbmA : hbmB;
            fused_step<<<128, 256, 0, stream>>>(
                xwTs + (long)tt * FH * 32, UbfS, bUs, alpha,
                hsin, hsout, cS, out1c + (long)tt * BB * HH,
                xwTm + (long)tt * NCMB * 32, UbfM, bUm, P, Bmbf,
                hmin, hmout, cM, out, (ch - 1) * TC + tt,
                do_s, do_m);
        }

        if (do_s) {
            // combined Wm+A projection for chunk ch (consumed next iteration)
            gemm_bf<64, 128><<<gcm, 256, 0, stream>>>(
                out1c, (long)BB * HH, (long)HH, Wcomb, bcomb, xwTm, NCMB, HH);
        }
    }
}